// Round 7
// baseline (17295.677 us; speedup 1.0000x reference)
//
#include <hip/hip_runtime.h>

#define SEQ  2048
#define NB   8
#define HD   256
#define G3   768
#define NV   100
#define NWG  4     // gru_scan workgroups
#define NTS  768   // gru_scan threads/WG = 12 waves

typedef float f32x4 __attribute__((ext_vector_type(4)));
typedef int   i32x4 __attribute__((ext_vector_type(4)));

#define INV33 1.16415321826934814453125e-10f  // 2^-33

__device__ __forceinline__ float sigm(float x) {
  x = fminf(fmaxf(x, -30.f), 30.f);
  return 1.f / (1.f + __expf(-x));
}
__device__ __forceinline__ float tanh_fast(float x) {
  x = fminf(fmaxf(x, -15.f), 15.f);
  float e = __expf(2.f * x);
  return (e - 1.f) / (e + 1.f);
}

// ---------------- K1: xg lookup table: table[v][g] = emb[v]·w_ih[g] + b_ih[g]
__global__ __launch_bounds__(256) void build_table(
    const float* __restrict__ emb, const float* __restrict__ w_ih,
    const float* __restrict__ b_ih, float* __restrict__ table) {
  __shared__ float eL[256];
  __shared__ float wL[256][37];
  int v = blockIdx.x, tid = threadIdx.x;
  eL[tid] = emb[v * HD + tid];
  for (int gt = 0; gt < 3; ++gt) {
    float acc = b_ih[gt * 256 + tid];
    for (int e0 = 0; e0 < HD; e0 += 32) {
      __syncthreads();
      #pragma unroll
      for (int i = 0; i < 32; ++i) {
        int idx = tid + i * 256;
        int r = idx >> 5, c = idx & 31;
        wL[r][c] = w_ih[(size_t)(gt * 256 + r) * HD + e0 + c];
      }
      __syncthreads();
      #pragma unroll
      for (int c = 0; c < 32; ++c) acc += eL[e0 + c] * wL[tid][c];
    }
    table[(size_t)v * G3 + gt * 256 + tid] = acc;
  }
}

// ---------------- K2: distributed GRU scan, 4 WGs. WG k owns hidden units
// j in [64k,64k+64) and gate-triple n-cols {j, 256+j, 512+j} (12 tiles), so
// gates are fully local. 12 waves -> 1 n-tile/wave = 32 resident weight VGPRs
// (two signed i8 planes; rounds 4-6 showed the allocator refuses >128-reg
// residency, causing 620 MB/dispatch scratch refetch). h state crosses WGs via
// a double-buffered 4 KB global buffer (16 rows x 256: rows 0-7 = hi8(q_h),
// rows 8-15 = lou-128) + device-scope atomic counter with threadfence
// release/acquire (per-XCD L2 non-coherence). Fixed-point math identical to
// the round-3-verified kernel: q_h = hi8*256+lou, q_w = wh*256+wl,
// hg = (a1*2^16 + a2*2^8 + ccx + 128*sum_k(q_w))*2^-33 + b_hh.
__global__ void __launch_bounds__(NTS) gru_scan(
    const int* __restrict__ x, const float* __restrict__ w_hh,
    const float* __restrict__ b_hh, const float* __restrict__ table,
    signed char* __restrict__ hG, unsigned* __restrict__ cnt,
    float* __restrict__ all_h, float* __restrict__ h_last) {
  __shared__ float hg[8][192];   // per-WG gate inputs: cols 0-63 r, 64-127 z, 128-191 n
  const int k = blockIdx.x;
  int tid = threadIdx.x;
  int lane = tid & 63, w = tid >> 6;        // wave 0..11
  int ncol = lane & 15, quad = lane >> 4;

  // resident weights: wave w -> gate g=w>>2, pair=w&3; B col row = n index
  int gate = w >> 2, pair = w & 3;
  int row = gate * 256 + k * 64 + pair * 16 + ncol;
  i32x4 bh[4], bl[4];
  int sw = 0;
  #pragma unroll
  for (int c = 0; c < 4; ++c) {
    const float* p = w_hh + (size_t)row * HD + c * 64 + quad * 16;
    unsigned hw[4] = {0u, 0u, 0u, 0u}, lw[4] = {0u, 0u, 0u, 0u};
    #pragma unroll
    for (int e = 0; e < 16; ++e) {
      float f = p[e];
      int q = __float2int_rn(f * 262144.f);          // w * 2^18
      q = max(-16383, min(16383, q));
      int lo = (int)(signed char)(q & 255);          // signed low byte
      int hi = (q - lo) >> 8;                        // in [-64, 64]
      sw += q;
      int u = e >> 2, sh = (e & 3) * 8;
      hw[u] |= ((unsigned)(hi & 255)) << sh;
      lw[u] |= ((unsigned)(lo & 255)) << sh;
    }
    bh[c] = (i32x4){(int)hw[0], (int)hw[1], (int)hw[2], (int)hw[3]};
    bl[c] = (i32x4){(int)lw[0], (int)lw[1], (int)lw[2], (int)lw[3]};
  }
  sw += __shfl_xor(sw, 16);
  sw += __shfl_xor(sw, 32);                          // full-K sum of q_w for row
  float Cn = b_hh[row] + 128.f * (float)sw * INV33;

  // gate identity: tid<512: batch gb, local unit ln, global unit gj
  bool isg = tid < 512;
  int gb = tid >> 6;                                 // 0..7 when isg
  int ln = tid & 63;
  int gj = k * 64 + ln;
  float hreg = 0.f, xr = 0.f, xz = 0.f, xn = 0.f;
  if (isg) {
    int v = x[gb * SEQ];
    const float* tr = table + (size_t)v * G3 + gj;
    xr = tr[0]; xz = tr[256]; xn = tr[512];
  }

  int a_off = ncol * 256 + quad * 16;                // A row m = lane&15

  for (int t = 0; t < SEQ; ++t) {
    const signed char* hc = hG + (t & 1) * 4096;
    i32x4 a[4];
    #pragma unroll
    for (int c = 0; c < 4; ++c)
      a[c] = *(const i32x4*)(hc + a_off + c * 64);
    i32x4 A1 = {0, 0, 0, 0}, A2 = {0, 0, 0, 0};
    #pragma unroll
    for (int c = 0; c < 4; ++c) {
      A1 = __builtin_amdgcn_mfma_i32_16x16x64_i8(a[c], bh[c], A1, 0, 0, 0);
      A2 = __builtin_amdgcn_mfma_i32_16x16x64_i8(a[c], bl[c], A2, 0, 0, 0);
    }
    #pragma unroll
    for (int i = 0; i < 4; ++i) {
      int cc = A1[i] * 256 + A2[i];                  // |cc| < 2^30
      int cx = __shfl_xor(cc, 32);
      if (quad < 2) {
        hg[quad * 4 + i][w * 16 + ncol] =
            ((float)A1[i] * 65536.f + (float)A2[i] * 256.f + (float)cx) * INV33 + Cn;
      }
    }
    __syncthreads();                                 // hg ready
    signed char* hn = hG + ((t + 1) & 1) * 4096;
    if (isg) {
      float hr = hg[gb][ln];
      float hz = hg[gb][64 + ln];
      float hnv = hg[gb][128 + ln];
      float r = sigm(xr + hr);
      float z = sigm(xz + hz);
      float n = tanh_fast(xn + r * hnv);
      float h = (1.f - z) * n + z * hreg;
      hreg = h;
      int q = min(__float2int_rn(h * 32768.f), 32767);
      int lou = q & 255;
      int hi8 = (q - lou) >> 8;
      hn[gb * 256 + gj] = (signed char)hi8;
      hn[(gb + 8) * 256 + gj] = (signed char)(lou - 128);
      all_h[((size_t)gb * SEQ + t) * HD + gj] = h;
      int tn = (t + 1 < SEQ) ? t + 1 : t;            // prefetch next xg
      int v = x[gb * SEQ + tn];
      const float* tr = table + (size_t)v * G3 + gj;
      xr = tr[0]; xz = tr[256]; xn = tr[512];
    }
    // cross-WG step barrier (device scope)
    __threadfence();                                 // release hn stores
    __syncthreads();
    if (tid == 0) {
      atomicAdd(cnt, 1u);
      unsigned target = (unsigned)NWG * (unsigned)(t + 1);
      while (atomicAdd(cnt, 0u) < target) __builtin_amdgcn_s_sleep(2);
    }
    __syncthreads();
    __threadfence();                                 // acquire remote h
  }
  if (isg) h_last[gb * HD + gj] = hreg;
}

// ---------------- generic f32 GEMM  C[M,N] = A[M,K]·W[N,K]^T + bias
template<int ACT>
__global__ __launch_bounds__(256) void gemm_bias(
    const float* __restrict__ A, int lda,
    const float* __restrict__ W, const float* __restrict__ bias,
    float* __restrict__ C, int ldc, int N, int K) {
  __shared__ float As[128][36];
  __shared__ float Ws[64][36];
  int tid = threadIdx.x;
  int m0 = blockIdx.y * 128, n0 = blockIdx.x * 64;
  int ml = tid & 31, g = tid >> 5;
  float acc[4][8];
  #pragma unroll
  for (int i = 0; i < 4; ++i)
    #pragma unroll
    for (int jj = 0; jj < 8; ++jj) acc[i][jj] = 0.f;
  for (int k0 = 0; k0 < K; k0 += 32) {
    __syncthreads();
    #pragma unroll
    for (int i = 0; i < 4; ++i) {
      int idx = tid + i * 256;
      int r = idx >> 3, c4 = (idx & 7) * 4;
      *(f32x4*)&As[r][c4] = *(const f32x4*)&A[(size_t)(m0 + r) * lda + k0 + c4];
    }
    #pragma unroll
    for (int i = 0; i < 2; ++i) {
      int idx = tid + i * 256;
      int r = idx >> 3, c4 = (idx & 7) * 4;
      f32x4 wv = {0.f, 0.f, 0.f, 0.f};
      if (n0 + r < N) wv = *(const f32x4*)&W[(size_t)(n0 + r) * K + k0 + c4];
      *(f32x4*)&Ws[r][c4] = wv;
    }
    __syncthreads();
    #pragma unroll
    for (int k4 = 0; k4 < 32; k4 += 4) {
      f32x4 av[4], wv8[8];
      #pragma unroll
      for (int i = 0; i < 4; ++i) av[i] = *(const f32x4*)&As[ml + i * 32][k4];
      #pragma unroll
      for (int jj = 0; jj < 8; ++jj) wv8[jj] = *(const f32x4*)&Ws[g * 8 + jj][k4];
      #pragma unroll
      for (int kk = 0; kk < 4; ++kk)
        #pragma unroll
        for (int i = 0; i < 4; ++i)
          #pragma unroll
          for (int jj = 0; jj < 8; ++jj)
            acc[i][jj] += av[i][kk] * wv8[jj][kk];
    }
  }
  #pragma unroll
  for (int i = 0; i < 4; ++i) {
    int m = m0 + ml + i * 32;
    #pragma unroll
    for (int jj = 0; jj < 8; ++jj) {
      int n = n0 + g * 8 + jj;
      if (n < N) {
        float val = acc[i][jj] + bias[n];
        if (ACT) val = tanh_fast(val);
        C[(size_t)m * ldc + n] = val;
      }
    }
  }
}

// ---------------- comb GEMM: A = [all_h | ctx] split-K (K=512), tanh epilogue
__global__ __launch_bounds__(256) void gemm_bias_cat(
    const float* __restrict__ A1, const float* __restrict__ A2,
    const float* __restrict__ W, const float* __restrict__ bias,
    float* __restrict__ C) {
  __shared__ float As[128][36];
  __shared__ float Ws[64][36];
  const int K = 512;
  int tid = threadIdx.x;
  int m0 = blockIdx.y * 128, n0 = blockIdx.x * 64;
  int ml = tid & 31, g = tid >> 5;
  float acc[4][8];
  #pragma unroll
  for (int i = 0; i < 4; ++i)
    #pragma unroll
    for (int jj = 0; jj < 8; ++jj) acc[i][jj] = 0.f;
  for (int k0 = 0; k0 < K; k0 += 32) {
    const float* src = (k0 < 256) ? A1 : A2;
    int kb = (k0 < 256) ? k0 : k0 - 256;
    __syncthreads();
    #pragma unroll
    for (int i = 0; i < 4; ++i) {
      int idx = tid + i * 256;
      int r = idx >> 3, c4 = (idx & 7) * 4;
      *(f32x4*)&As[r][c4] = *(const f32x4*)&src[(size_t)(m0 + r) * 256 + kb + c4];
    }
    #pragma unroll
    for (int i = 0; i < 2; ++i) {
      int idx = tid + i * 256;
      int r = idx >> 3, c4 = (idx & 7) * 4;
      *(f32x4*)&Ws[r][c4] = *(const f32x4*)&W[(size_t)(n0 + r) * K + k0 + c4];
    }
    __syncthreads();
    #pragma unroll
    for (int k4 = 0; k4 < 32; k4 += 4) {
      f32x4 av[4], wv8[8];
      #pragma unroll
      for (int i = 0; i < 4; ++i) av[i] = *(const f32x4*)&As[ml + i * 32][k4];
      #pragma unroll
      for (int jj = 0; jj < 8; ++jj) wv8[jj] = *(const f32x4*)&Ws[g * 8 + jj][k4];
      #pragma unroll
      for (int kk = 0; kk < 4; ++kk)
        #pragma unroll
        for (int i = 0; i < 4; ++i)
          #pragma unroll
          for (int jj = 0; jj < 8; ++jj)
            acc[i][jj] += av[i][kk] * wv8[jj][kk];
    }
  }
  #pragma unroll
  for (int i = 0; i < 4; ++i) {
    int m = m0 + ml + i * 32;
    #pragma unroll
    for (int jj = 0; jj < 8; ++jj) {
      int n = n0 + g * 8 + jj;
      C[(size_t)m * 256 + n] = tanh_fast(acc[i][jj] + bias[n]);
    }
  }
}

// ---------------- K4: causal flash attention, q-tile 32 / k-tile 16, all f32.
// Block (jb, b) handles q-tiles jb and 63-jb (balances the causal triangle).
__global__ __launch_bounds__(256) void attention_kernel(
    const float* __restrict__ all_h, const float* __restrict__ keys,
    float* __restrict__ ctx) {
  __shared__ float Qs[32][260];
  __shared__ float Ks[16][260];
  __shared__ float Hs[16 * 256];
  __shared__ float Sl[32][17];
  __shared__ float mL[32], lL[32], aL[32];
  int b = blockIdx.y, jb = blockIdx.x, tid = threadIdx.x;
  const float* hb = all_h + (size_t)b * SEQ * HD;
  const float* kb = keys  + (size_t)b * SEQ * HD;
  int qg = tid & 15, hi = tid >> 4;
  int r0 = qg * 2, r1 = r0 + 1;
  for (int phase = 0; phase < 2; ++phase) {
    int qt = phase ? (63 - jb) : jb;
    int q0 = qt * 32;
    __syncthreads();
    #pragma unroll
    for (int i = 0; i < 8; ++i) {           // stage Q 32x256
      int idx = tid + i * 256;
      int r = idx >> 6, c = (idx & 63) * 4;
      *(f32x4*)&Qs[r][c] = *(const f32x4*)&hb[(size_t)(q0 + r) * HD + c];
    }
    if (tid < 32) { mL[tid] = -3e38f; lL[tid] = 0.f; }
    float O0[16], O1[16];
    #pragma unroll
    for (int c = 0; c < 16; ++c) { O0[c] = 0.f; O1[c] = 0.f; }
    int nkt = 2 * (qt + 1);
    for (int kt = 0; kt < nkt; ++kt) {
      int k0 = kt * 16;
      __syncthreads();
      #pragma unroll
      for (int i = 0; i < 4; ++i) {         // stage K + V (f32), 16x256 each
        int idx = tid + i * 256;
        int r = idx >> 6, c = (idx & 63) * 4;
        *(f32x4*)&Ks[r][c] = *(const f32x4*)&kb[(size_t)(k0 + r) * HD + c];
        *(f32x4*)&Hs[r * 256 + c] = *(const f32x4*)&hb[(size_t)(k0 + r) * HD + c];
      }
      __syncthreads();
      int kc = hi;
      float sc0 = 0.f, sc1 = 0.f;
      #pragma unroll 8
      for (int c = 0; c < 64; ++c) {
        f32x4 kv  = *(const f32x4*)&Ks[kc][c * 4];
        f32x4 q0v = *(const f32x4*)&Qs[r0][c * 4];
        f32x4 q1v = *(const f32x4*)&Qs[r1][c * 4];
        sc0 += q0v[0]*kv[0] + q0v[1]*kv[1] + q0v[2]*kv[2] + q0v[3]*kv[3];
        sc1 += q1v[0]*kv[0] + q1v[1]*kv[1] + q1v[2]*kv[2] + q1v[3]*kv[3];
      }
      int kabs = k0 + kc;
      Sl[r0][kc] = (kabs <= q0 + r0) ? sc0 : -3e38f;
      Sl[r1][kc] = (kabs <= q0 + r1) ? sc1 : -3e38f;
      __syncthreads();
      if (tid < 32) {                       // online softmax per q-row
        float mo = mL[tid], mn = mo;
        #pragma unroll
        for (int c = 0; c < 16; ++c) mn = fmaxf(mn, Sl[tid][c]);
        float al = __expf(mo - mn);
        float sm = 0.f;
        #pragma unroll
        for (int c = 0; c < 16; ++c) {
          float p = __expf(Sl[tid][c] - mn);
          Sl[tid][c] = p; sm += p;
        }
        lL[tid] = lL[tid] * al + sm;
        mL[tid] = mn;
        aL[tid] = al;
      }
      __syncthreads();
      float a0 = aL[r0], a1 = aL[r1];
      #pragma unroll
      for (int c = 0; c < 16; ++c) { O0[c] *= a0; O1[c] *= a1; }
      #pragma unroll
      for (int k = 0; k < 16; ++k) {
        float p0 = Sl[r0][k], p1 = Sl[r1][k];
        #pragma unroll
        for (int c4 = 0; c4 < 4; ++c4) {
          f32x4 hh = *(const f32x4*)&Hs[k * 256 + hi * 16 + c4 * 4];
          O0[c4*4+0] += p0 * hh[0]; O0[c4*4+1] += p0 * hh[1];
          O0[c4*4+2] += p0 * hh[2]; O0[c4*4+3] += p0 * hh[3];
          O1[c4*4+0] += p1 * hh[0]; O1[c4*4+1] += p1 * hh[1];
          O1[c4*4+2] += p1 * hh[2]; O1[c4*4+3] += p1 * hh[3];
        }
      }
    }
    float li0 = 1.f / lL[r0], li1 = 1.f / lL[r1];
    float* d0 = &ctx[((size_t)b * SEQ + q0 + r0) * 256 + hi * 16];
    float* d1 = &ctx[((size_t)b * SEQ + q0 + r1) * 256 + hi * 16];
    #pragma unroll
    for (int c4 = 0; c4 < 4; ++c4) {
      f32x4 v0, v1;
      #pragma unroll
      for (int c = 0; c < 4; ++c) { v0[c] = O0[c4*4+c] * li0; v1[c] = O1[c4*4+c] * li1; }
      *(f32x4*)&d0[c4*4] = v0;
      *(f32x4*)&d1[c4*4] = v1;
    }
  }
}

extern "C" void kernel_launch(void* const* d_in, const int* in_sizes, int n_in,
                              void* d_out, int out_size, void* d_ws, size_t ws_size,
                              hipStream_t stream) {
  (void)in_sizes; (void)n_in; (void)out_size; (void)ws_size;
  const int*   x      = (const int*)  d_in[0];
  const float* emb    = (const float*)d_in[1];
  const float* w_ih   = (const float*)d_in[2];
  const float* w_hh   = (const float*)d_in[3];
  const float* b_ih   = (const float*)d_in[4];
  const float* b_hh   = (const float*)d_in[5];
  const float* attn_w = (const float*)d_in[6];
  const float* attn_b = (const float*)d_in[7];
  const float* comb_w = (const float*)d_in[8];
  const float* comb_b = (const float*)d_in[9];
  const float* fc_w   = (const float*)d_in[10];
  const float* fc_b   = (const float*)d_in[11];
  float* out = (float*)d_out;

  // workspace layout (floats): table | all_h | keys(->combined) | ctx | hG | cnt
  float* ws    = (float*)d_ws;
  float* table = ws;                        // 100*768      =    76800
  float* all_h = table + 76800;             // 16384*256    =  4194304
  float* keys  = all_h + 4194304;           // 16384*256    =  4194304
  float* ctx   = keys  + 4194304;           // 16384*256    =  4194304
  signed char* hG = (signed char*)(ctx + 4194304);  // 2 x 4096 B, 16B aligned
  unsigned* cnt = (unsigned*)(hG + 8192);
  float* hlast = out + (size_t)NB * SEQ * NV;

  // init h buffer 0 to q_h = 0 (rows 0-7: hi8 = 0x00; rows 8-15: lou-128 = 0x80)
  hipMemsetAsync(hG, 0x00, 2048, stream);
  hipMemsetAsync(hG + 2048, 0x80, 2048, stream);
  hipMemsetAsync(cnt, 0, 4, stream);

  build_table<<<100, 256, 0, stream>>>(emb, w_ih, b_ih, table);
  gru_scan<<<NWG, NTS, 0, stream>>>(x, w_hh, b_hh, table, hG, cnt, all_h, hlast);
  // keys = all_h @ attn_w^T + attn_b
  gemm_bias<0><<<dim3(4, 128), 256, 0, stream>>>(all_h, 256, attn_w, attn_b, keys, 256, 256, 256);
  // ctx = softmax(causal(all_h @ keys^T)) @ all_h
  attention_kernel<<<dim3(32, 8), 256, 0, stream>>>(all_h, keys, ctx);
  // combined = tanh([all_h|ctx] @ comb_w^T + comb_b)  (into keys buffer)
  gemm_bias_cat<<<dim3(4, 128), 256, 0, stream>>>(all_h, ctx, comb_w, comb_b, keys);
  // out = combined @ fc_w^T + fc_b
  gemm_bias<0><<<dim3(2, 128), 256, 0, stream>>>(keys, 256, fc_w, fc_b, out, 100, 100, 256);
}

// Round 8
// 7586.523 us; speedup vs baseline: 2.2798x; 2.2798x over previous
//
#include <hip/hip_runtime.h>

#define SEQ  2048
#define NB   8
#define HD   256
#define G3   768
#define NV   100
#define NT2  512   // gru_scan threads = 8 waves

typedef float f32x4 __attribute__((ext_vector_type(4)));
typedef int   i32x4 __attribute__((ext_vector_type(4)));

#define INV26 1.490116119384765625e-8f   // 2^-26

__device__ __forceinline__ float sigm(float x) {
  x = fminf(fmaxf(x, -30.f), 30.f);
  return 1.f / (1.f + __expf(-x));
}
__device__ __forceinline__ float tanh_fast(float x) {
  x = fminf(fmaxf(x, -15.f), 15.f);
  float e = __expf(2.f * x);
  return (e - 1.f) / (e + 1.f);
}

// ---------------- K1: xg lookup table: table[v][g] = emb[v]·w_ih[g] + b_ih[g]
__global__ __launch_bounds__(256) void build_table(
    const float* __restrict__ emb, const float* __restrict__ w_ih,
    const float* __restrict__ b_ih, float* __restrict__ table) {
  __shared__ float eL[256];
  __shared__ float wL[256][37];
  int v = blockIdx.x, tid = threadIdx.x;
  eL[tid] = emb[v * HD + tid];
  for (int gt = 0; gt < 3; ++gt) {
    float acc = b_ih[gt * 256 + tid];
    for (int e0 = 0; e0 < HD; e0 += 32) {
      __syncthreads();
      #pragma unroll
      for (int i = 0; i < 32; ++i) {
        int idx = tid + i * 256;
        int r = idx >> 5, c = idx & 31;
        wL[r][c] = w_ih[(size_t)(gt * 256 + r) * HD + e0 + c];
      }
      __syncthreads();
      #pragma unroll
      for (int c = 0; c < 32; ++c) acc += eL[e0 + c] * wL[tid][c];
    }
    table[(size_t)v * G3 + gt * 256 + tid] = acc;
  }
}

// ---------------- K2: GRU scan, single WG, 8 waves. Weights single-plane i8
// (q_w = round(w*2^11), |w|<=1/16): wave w owns n-tiles 6w..6w+5; tiles 0-1
// resident in VGPRs (32 regs), tiles 2-5 in LDS (128 KB) stored in MFMA
// fragment order (lane*16 contiguous -> 2-way bank aliasing, free).
// Rounds 4-6 showed the allocator caps ~128 VGPRs and scratch-spills larger
// sets (200 KB/step L2 refetch = the 4.7us/step); round 7 showed cross-WG
// fencing costs more. This design needs ~110 regs: no spill, no cross-WG.
// h stays i16 via packed A rows (0-7 = hi8(q_h), 8-15 = lou-128); one i8 MFMA
// chain gives both row-halves; recombine:
//   hg = (256*a_hi + a_lo_x + 128*sum_k q_w) * 2^-26 + b_hh
// C/D: col=lane&15, row=(lane>>4)*4+reg; rows b and b+8 differ by lane xor 32.
__global__ void __launch_bounds__(NT2) gru_scan(
    const int* __restrict__ x, const float* __restrict__ w_hh,
    const float* __restrict__ b_hh, const float* __restrict__ table,
    float* __restrict__ all_h, float* __restrict__ h_last) {
  __shared__ __align__(16) signed char wlds[131072];  // 8 waves x 4 tiles x 4 chunks x 1KB
  __shared__ __align__(16) signed char hpk[16 * 272];
  __shared__ float hg[8 * G3];
  int tid = threadIdx.x;
  int lane = tid & 63, wv = tid >> 6;       // 8 waves
  int ncol = lane & 15, quad = lane >> 4;

  // init hpk to q=0: hi=0 (rows 0-7), lou-128 = -128 (rows 8-15)
  for (int i = tid; i < 16 * 272; i += NT2)
    hpk[i] = (i < 8 * 272) ? 0 : (signed char)-128;

  // quantize weights; wave wv owns n-tiles wv*6..wv*6+5
  i32x4 breg[2][4];
  float Cn[6];
  #pragma unroll
  for (int t6 = 0; t6 < 6; ++t6) {
    int row = (wv * 6 + t6) * 16 + ncol;
    int sw = 0;
    #pragma unroll
    for (int c = 0; c < 4; ++c) {
      const float* p = w_hh + (size_t)row * HD + c * 64 + quad * 16;
      unsigned pw[4] = {0u, 0u, 0u, 0u};
      #pragma unroll
      for (int e = 0; e < 16; ++e) {
        int q = __float2int_rn(p[e] * 2048.f);       // w * 2^11
        q = max(-127, min(127, q));
        sw += q;
        pw[e >> 2] |= ((unsigned)(q & 255)) << ((e & 3) * 8);
      }
      i32x4 frag = (i32x4){(int)pw[0], (int)pw[1], (int)pw[2], (int)pw[3]};
      if (t6 < 2) breg[t6][c] = frag;
      else {
        int base = (((wv * 4 + (t6 - 2)) * 4 + c) << 10) + lane * 16;
        *(i32x4*)&wlds[base] = frag;
      }
    }
    sw += __shfl_xor(sw, 16);
    sw += __shfl_xor(sw, 32);                        // full-K sum of q_w for row
    Cn[t6] = b_hh[row] + 128.f * (float)sw * INV26;
  }

  // gate identity: items (b = b0 + 2*it, j), 4 items/thread
  int j = tid & 255, b0 = tid >> 8;
  float hreg[4] = {0.f, 0.f, 0.f, 0.f};
  float xrp[4], xzp[4], xnp[4];
  #pragma unroll
  for (int it = 0; it < 4; ++it) {
    int b = b0 + 2 * it;
    int v = x[b * SEQ];
    const float* tr = table + (size_t)v * G3 + j;
    xrp[it] = tr[0]; xzp[it] = tr[256]; xnp[it] = tr[512];
  }

  int a_base = ncol * 272 + quad * 16;

  for (int t = 0; t < SEQ; ++t) {
    __syncthreads();                                 // hpk (and LDS weights) ready
    i32x4 a[4];
    #pragma unroll
    for (int c = 0; c < 4; ++c)
      a[c] = *(const i32x4*)&hpk[a_base + c * 64];
    #pragma unroll
    for (int t6 = 0; t6 < 6; ++t6) {
      i32x4 acc = {0, 0, 0, 0};
      if (t6 < 2) {
        #pragma unroll
        for (int c = 0; c < 4; ++c)
          acc = __builtin_amdgcn_mfma_i32_16x16x64_i8(a[c], breg[t6][c], acc, 0, 0, 0);
      } else {
        i32x4 bf[4];
        #pragma unroll
        for (int c = 0; c < 4; ++c)
          bf[c] = *(const i32x4*)&wlds[(((wv * 4 + (t6 - 2)) * 4 + c) << 10) + lane * 16];
        #pragma unroll
        for (int c = 0; c < 4; ++c)
          acc = __builtin_amdgcn_mfma_i32_16x16x64_i8(a[c], bf[c], acc, 0, 0, 0);
      }
      int n = (wv * 6 + t6) * 16 + ncol;
      #pragma unroll
      for (int i = 0; i < 4; ++i) {
        int ax = __shfl_xor(acc[i], 32);             // rows b+8 (h-lo plane)
        if (quad < 2) {
          hg[(quad * 4 + i) * G3 + n] =
              ((float)acc[i] * 256.f + (float)ax) * INV26 + Cn[t6];
        }
      }
    }
    __syncthreads();                                 // hg ready
    #pragma unroll
    for (int it = 0; it < 4; ++it) {
      int b = b0 + 2 * it;
      float hr = hg[b * G3 + j];
      float hz = hg[b * G3 + 256 + j];
      float hn = hg[b * G3 + 512 + j];
      float r = sigm(xrp[it] + hr);
      float z = sigm(xzp[it] + hz);
      float n = tanh_fast(xnp[it] + r * hn);
      float h = (1.f - z) * n + z * hreg[it];
      hreg[it] = h;
      int q = min(__float2int_rn(h * 32768.f), 32767);
      int lou = q & 255;
      int hi8 = (q - lou) >> 8;
      hpk[b * 272 + j] = (signed char)hi8;
      hpk[(b + 8) * 272 + j] = (signed char)(lou - 128);
      all_h[((size_t)b * SEQ + t) * HD + j] = h;
    }
    {                                                // prefetch next step's table rows
      int tn = (t + 1 < SEQ) ? t + 1 : t;
      #pragma unroll
      for (int it = 0; it < 4; ++it) {
        int b = b0 + 2 * it;
        int v = x[b * SEQ + tn];
        const float* tr = table + (size_t)v * G3 + j;
        xrp[it] = tr[0]; xzp[it] = tr[256]; xnp[it] = tr[512];
      }
    }
  }
  #pragma unroll
  for (int it = 0; it < 4; ++it) {
    int b = b0 + 2 * it;
    h_last[b * HD + j] = hreg[it];
  }
}

// ---------------- generic f32 GEMM  C[M,N] = A[M,K]·W[N,K]^T + bias
template<int ACT>
__global__ __launch_bounds__(256) void gemm_bias(
    const float* __restrict__ A, int lda,
    const float* __restrict__ W, const float* __restrict__ bias,
    float* __restrict__ C, int ldc, int N, int K) {
  __shared__ float As[128][36];
  __shared__ float Ws[64][36];
  int tid = threadIdx.x;
  int m0 = blockIdx.y * 128, n0 = blockIdx.x * 64;
  int ml = tid & 31, g = tid >> 5;
  float acc[4][8];
  #pragma unroll
  for (int i = 0; i < 4; ++i)
    #pragma unroll
    for (int jj = 0; jj < 8; ++jj) acc[i][jj] = 0.f;
  for (int k0 = 0; k0 < K; k0 += 32) {
    __syncthreads();
    #pragma unroll
    for (int i = 0; i < 4; ++i) {
      int idx = tid + i * 256;
      int r = idx >> 3, c4 = (idx & 7) * 4;
      *(f32x4*)&As[r][c4] = *(const f32x4*)&A[(size_t)(m0 + r) * lda + k0 + c4];
    }
    #pragma unroll
    for (int i = 0; i < 2; ++i) {
      int idx = tid + i * 256;
      int r = idx >> 3, c4 = (idx & 7) * 4;
      f32x4 wv = {0.f, 0.f, 0.f, 0.f};
      if (n0 + r < N) wv = *(const f32x4*)&W[(size_t)(n0 + r) * K + k0 + c4];
      *(f32x4*)&Ws[r][c4] = wv;
    }
    __syncthreads();
    #pragma unroll
    for (int k4 = 0; k4 < 32; k4 += 4) {
      f32x4 av[4], wv8[8];
      #pragma unroll
      for (int i = 0; i < 4; ++i) av[i] = *(const f32x4*)&As[ml + i * 32][k4];
      #pragma unroll
      for (int jj = 0; jj < 8; ++jj) wv8[jj] = *(const f32x4*)&Ws[g * 8 + jj][k4];
      #pragma unroll
      for (int kk = 0; kk < 4; ++kk)
        #pragma unroll
        for (int i = 0; i < 4; ++i)
          #pragma unroll
          for (int jj = 0; jj < 8; ++jj)
            acc[i][jj] += av[i][kk] * wv8[jj][kk];
    }
  }
  #pragma unroll
  for (int i = 0; i < 4; ++i) {
    int m = m0 + ml + i * 32;
    #pragma unroll
    for (int jj = 0; jj < 8; ++jj) {
      int n = n0 + g * 8 + jj;
      if (n < N) {
        float val = acc[i][jj] + bias[n];
        if (ACT) val = tanh_fast(val);
        C[(size_t)m * ldc + n] = val;
      }
    }
  }
}

// ---------------- comb GEMM: A = [all_h | ctx] split-K (K=512), tanh epilogue
__global__ __launch_bounds__(256) void gemm_bias_cat(
    const float* __restrict__ A1, const float* __restrict__ A2,
    const float* __restrict__ W, const float* __restrict__ bias,
    float* __restrict__ C) {
  __shared__ float As[128][36];
  __shared__ float Ws[64][36];
  const int K = 512;
  int tid = threadIdx.x;
  int m0 = blockIdx.y * 128, n0 = blockIdx.x * 64;
  int ml = tid & 31, g = tid >> 5;
  float acc[4][8];
  #pragma unroll
  for (int i = 0; i < 4; ++i)
    #pragma unroll
    for (int jj = 0; jj < 8; ++jj) acc[i][jj] = 0.f;
  for (int k0 = 0; k0 < K; k0 += 32) {
    const float* src = (k0 < 256) ? A1 : A2;
    int kb = (k0 < 256) ? k0 : k0 - 256;
    __syncthreads();
    #pragma unroll
    for (int i = 0; i < 4; ++i) {
      int idx = tid + i * 256;
      int r = idx >> 3, c4 = (idx & 7) * 4;
      *(f32x4*)&As[r][c4] = *(const f32x4*)&src[(size_t)(m0 + r) * 256 + kb + c4];
    }
    #pragma unroll
    for (int i = 0; i < 2; ++i) {
      int idx = tid + i * 256;
      int r = idx >> 3, c4 = (idx & 7) * 4;
      *(f32x4*)&Ws[r][c4] = *(const f32x4*)&W[(size_t)(n0 + r) * K + k0 + c4];
    }
    __syncthreads();
    #pragma unroll
    for (int k4 = 0; k4 < 32; k4 += 4) {
      f32x4 av[4], wv8[8];
      #pragma unroll
      for (int i = 0; i < 4; ++i) av[i] = *(const f32x4*)&As[ml + i * 32][k4];
      #pragma unroll
      for (int jj = 0; jj < 8; ++jj) wv8[jj] = *(const f32x4*)&Ws[g * 8 + jj][k4];
      #pragma unroll
      for (int kk = 0; kk < 4; ++kk)
        #pragma unroll
        for (int i = 0; i < 4; ++i)
          #pragma unroll
          for (int jj = 0; jj < 8; ++jj)
            acc[i][jj] += av[i][kk] * wv8[jj][kk];
    }
  }
  #pragma unroll
  for (int i = 0; i < 4; ++i) {
    int m = m0 + ml + i * 32;
    #pragma unroll
    for (int jj = 0; jj < 8; ++jj) {
      int n = n0 + g * 8 + jj;
      C[(size_t)m * 256 + n] = tanh_fast(acc[i][jj] + bias[n]);
    }
  }
}

// ---------------- K4: causal flash attention, q-tile 32 / k-tile 16, all f32.
// Qs/Ks XOR-swizzled (group ^ row-derived 3 bits) -> conflict-free score loop
// (unswizzled stride-260 gave 4-way conflicts, SQ_LDS_BANK_CONFLICT=6.8e7).
__global__ __launch_bounds__(256) void attention_kernel(
    const float* __restrict__ all_h, const float* __restrict__ keys,
    float* __restrict__ ctx) {
  __shared__ float Qs[32 * 256];
  __shared__ float Ks[16 * 256];
  __shared__ float Hs[16 * 256];
  __shared__ float Sl[32][17];
  __shared__ float mL[32], lL[32], aL[32];
  int b = blockIdx.y, jb = blockIdx.x, tid = threadIdx.x;
  const float* hb = all_h + (size_t)b * SEQ * HD;
  const float* kb = keys  + (size_t)b * SEQ * HD;
  int qg = tid & 15, hi = tid >> 4;
  int r0 = qg * 2, r1 = r0 + 1;
  int sq = qg & 7;                          // Q swizzle bits for rows r0,r1
  for (int phase = 0; phase < 2; ++phase) {
    int qt = phase ? (63 - jb) : jb;
    int q0 = qt * 32;
    __syncthreads();
    #pragma unroll
    for (int i = 0; i < 8; ++i) {           // stage Q 32x256 (swizzled)
      int idx = tid + i * 256;
      int r = idx >> 6, cg = idx & 63;
      *(f32x4*)&Qs[r * 256 + ((cg ^ ((r >> 1) & 7)) << 2)] =
          *(const f32x4*)&hb[(size_t)(q0 + r) * HD + cg * 4];
    }
    if (tid < 32) { mL[tid] = -3e38f; lL[tid] = 0.f; }
    float O0[16], O1[16];
    #pragma unroll
    for (int c = 0; c < 16; ++c) { O0[c] = 0.f; O1[c] = 0.f; }
    int nkt = 2 * (qt + 1);
    for (int kt = 0; kt < nkt; ++kt) {
      int k0 = kt * 16;
      __syncthreads();
      #pragma unroll
      for (int i = 0; i < 4; ++i) {         // stage K (swizzled) + V, 16x256 each
        int idx = tid + i * 256;
        int r = idx >> 6, cg = idx & 63;
        *(f32x4*)&Ks[r * 256 + ((cg ^ (r & 7)) << 2)] =
            *(const f32x4*)&kb[(size_t)(k0 + r) * HD + cg * 4];
        *(f32x4*)&Hs[r * 256 + cg * 4] = *(const f32x4*)&hb[(size_t)(k0 + r) * HD + cg * 4];
      }
      __syncthreads();
      int kc = hi;
      int sk = kc & 7;
      float sc0 = 0.f, sc1 = 0.f;
      #pragma unroll 8
      for (int c = 0; c < 64; ++c) {
        f32x4 kv  = *(const f32x4*)&Ks[kc * 256 + ((c ^ sk) << 2)];
        f32x4 q0v = *(const f32x4*)&Qs[r0 * 256 + ((c ^ sq) << 2)];
        f32x4 q1v = *(const f32x4*)&Qs[r1 * 256 + ((c ^ sq) << 2)];
        sc0 += q0v[0]*kv[0] + q0v[1]*kv[1] + q0v[2]*kv[2] + q0v[3]*kv[3];
        sc1 += q1v[0]*kv[0] + q1v[1]*kv[1] + q1v[2]*kv[2] + q1v[3]*kv[3];
      }
      int kabs = k0 + kc;
      Sl[r0][kc] = (kabs <= q0 + r0) ? sc0 : -3e38f;
      Sl[r1][kc] = (kabs <= q0 + r1) ? sc1 : -3e38f;
      __syncthreads();
      if (tid < 32) {                       // online softmax per q-row
        float mo = mL[tid], mn = mo;
        #pragma unroll
        for (int c = 0; c < 16; ++c) mn = fmaxf(mn, Sl[tid][c]);
        float al = __expf(mo - mn);
        float sm = 0.f;
        #pragma unroll
        for (int c = 0; c < 16; ++c) {
          float p = __expf(Sl[tid][c] - mn);
          Sl[tid][c] = p; sm += p;
        }
        lL[tid] = lL[tid] * al + sm;
        mL[tid] = mn;
        aL[tid] = al;
      }
      __syncthreads();
      float a0 = aL[r0], a1 = aL[r1];
      #pragma unroll
      for (int c = 0; c < 16; ++c) { O0[c] *= a0; O1[c] *= a1; }
      #pragma unroll
      for (int k = 0; k < 16; ++k) {
        float p0 = Sl[r0][k], p1 = Sl[r1][k];
        #pragma unroll
        for (int c4 = 0; c4 < 4; ++c4) {
          f32x4 hh = *(const f32x4*)&Hs[k * 256 + hi * 16 + c4 * 4];
          O0[c4*4+0] += p0 * hh[0]; O0[c4*4+1] += p0 * hh[1];
          O0[c4*4+2] += p0 * hh[2]; O0[c4*4+3] += p0 * hh[3];
          O1[c4*4+0] += p1 * hh[0]; O1[c4*4+1] += p1 * hh[1];
          O1[c4*4+2] += p1 * hh[2]; O1[c4*4+3] += p1 * hh[3];
        }
      }
    }
    float li0 = 1.f / lL[r0], li1 = 1.f / lL[r1];
    float* d0 = &ctx[((size_t)b * SEQ + q0 + r0) * 256 + hi * 16];
    float* d1 = &ctx[((size_t)b * SEQ + q0 + r1) * 256 + hi * 16];
    #pragma unroll
    for (int c4 = 0; c4 < 4; ++c4) {
      f32x4 v0, v1;
      #pragma unroll
      for (int c = 0; c < 4; ++c) { v0[c] = O0[c4*4+c] * li0; v1[c] = O1[c4*4+c] * li1; }
      *(f32x4*)&d0[c4*4] = v0;
      *(f32x4*)&d1[c4*4] = v1;
    }
  }
}

extern "C" void kernel_launch(void* const* d_in, const int* in_sizes, int n_in,
                              void* d_out, int out_size, void* d_ws, size_t ws_size,
                              hipStream_t stream) {
  (void)in_sizes; (void)n_in; (void)out_size; (void)ws_size;
  const int*   x      = (const int*)  d_in[0];
  const float* emb    = (const float*)d_in[1];
  const float* w_ih   = (const float*)d_in[2];
  const float* w_hh   = (const float*)d_in[3];
  const float* b_ih   = (const float*)d_in[4];
  const float* b_hh   = (const float*)d_in[5];
  const float* attn_w = (const float*)d_in[6];
  const float* attn_b = (const float*)d_in[7];
  const float* comb_w = (const float*)d_in[8];
  const float* comb_b = (const float*)d_in[9];
  const float* fc_w   = (const float*)d_in[10];
  const float* fc_b   = (const float*)d_in[11];
  float* out = (float*)d_out;

  // workspace layout (floats): table | all_h | keys(->combined) | ctx
  float* ws    = (float*)d_ws;
  float* table = ws;                        // 100*768      =    76800
  float* all_h = table + 76800;             // 16384*256    =  4194304
  float* keys  = all_h + 4194304;           // 16384*256    =  4194304
  float* ctx   = keys  + 4194304;           // 16384*256    =  4194304
  float* hlast = out + (size_t)NB * SEQ * NV;

  build_table<<<100, 256, 0, stream>>>(emb, w_ih, b_ih, table);
  gru_scan<<<1, NT2, 0, stream>>>(x, w_hh, b_hh, table, all_h, hlast);
  // keys = all_h @ attn_w^T + attn_b
  gemm_bias<0><<<dim3(4, 128), 256, 0, stream>>>(all_h, 256, attn_w, attn_b, keys, 256, 256, 256);
  // ctx = softmax(causal(all_h @ keys^T)) @ all_h
  attention_kernel<<<dim3(32, 8), 256, 0, stream>>>(all_h, keys, ctx);
  // combined = tanh([all_h|ctx] @ comb_w^T + comb_b)  (into keys buffer)
  gemm_bias_cat<<<dim3(4, 128), 256, 0, stream>>>(all_h, ctx, comb_w, comb_b, keys);
  // out = combined @ fc_w^T + fc_b
  gemm_bias<0><<<dim3(2, 128), 256, 0, stream>>>(keys, 256, fc_w, fc_b, out, 100, 100, 256);
}

// Round 9
// 6074.020 us; speedup vs baseline: 2.8475x; 1.2490x over previous
//
#include <hip/hip_runtime.h>

#define SEQ  2048
#define NB   8
#define HD   256
#define G3   768
#define NV   100
#define NTS  1024  // gru_scan threads = 16 waves

typedef float f32x4 __attribute__((ext_vector_type(4)));
typedef int   i32x4 __attribute__((ext_vector_type(4)));

#define INV26 1.490116119384765625e-8f   // 2^-26

__device__ __forceinline__ float sigm(float x) {
  x = fminf(fmaxf(x, -30.f), 30.f);
  return 1.f / (1.f + __expf(-x));
}
__device__ __forceinline__ float tanh_fast(float x) {
  x = fminf(fmaxf(x, -15.f), 15.f);
  float e = __expf(2.f * x);
  return (e - 1.f) / (e + 1.f);
}

// ---------------- K1: xg lookup table: table[v][g] = emb[v]·w_ih[g] + b_ih[g]
__global__ __launch_bounds__(256) void build_table(
    const float* __restrict__ emb, const float* __restrict__ w_ih,
    const float* __restrict__ b_ih, float* __restrict__ table) {
  __shared__ float eL[256];
  __shared__ float wL[256][37];
  int v = blockIdx.x, tid = threadIdx.x;
  eL[tid] = emb[v * HD + tid];
  for (int gt = 0; gt < 3; ++gt) {
    float acc = b_ih[gt * 256 + tid];
    for (int e0 = 0; e0 < HD; e0 += 32) {
      __syncthreads();
      #pragma unroll
      for (int i = 0; i < 32; ++i) {
        int idx = tid + i * 256;
        int r = idx >> 5, c = idx & 31;
        wL[r][c] = w_ih[(size_t)(gt * 256 + r) * HD + e0 + c];
      }
      __syncthreads();
      #pragma unroll
      for (int c = 0; c < 32; ++c) acc += eL[e0 + c] * wL[tid][c];
    }
    table[(size_t)v * G3 + gt * 256 + tid] = acc;
  }
}

// ---------------- K2: GRU scan, single WG, 16 waves. Single-plane i8 weights
// (q_w = round(w*2^11), |w|<=1/16): wave wv owns n-tiles 3wv..3wv+2; tile 0 in
// VGPRs (16 regs), tiles 1-2 in wave-private LDS (128 KB total) in MFMA
// fragment order (lane*16 contiguous, 2-way bank aliasing = free).
// vs round 8 (8 waves x 6 tiles): halves each wave's serial MFMA/ds chain and
// doubles waves/SIMD (2->4); loop live-set ~75 regs so the 128-reg budget from
// amdgpu_waves_per_eu(4,4) leaves no scratch (round 8's FETCH=592 MB = 560
// B/thread/step scratch-reload signature).
// h stays i16 via packed A rows (0-7 = hi8(q_h), 8-15 = lou-128); one i8 MFMA
// chain gives both halves; recombine (verified round 8):
//   hg = (256*a_hi + a_lo_x + 128*sum_k q_w) * 2^-26 + b_hh
// C/D: col=lane&15, row=(lane>>4)*4+reg; rows b and b+8 differ by lane xor 32.
__global__ void __launch_bounds__(NTS)
__attribute__((amdgpu_waves_per_eu(4, 4)))
gru_scan(
    const int* __restrict__ x, const float* __restrict__ w_hh,
    const float* __restrict__ b_hh, const float* __restrict__ table,
    float* __restrict__ all_h, float* __restrict__ h_last) {
  __shared__ __align__(16) signed char wlds[131072];  // 16 waves x 2 tiles x 4 KB
  __shared__ __align__(16) signed char hpk[16 * 272];
  __shared__ float hg[8 * G3];
  int tid = threadIdx.x;
  int lane = tid & 63, wv = tid >> 6;       // 16 waves
  int ncol = lane & 15, quad = lane >> 4;

  // init hpk to q=0: hi=0 (rows 0-7), lou-128 = -128 (rows 8-15)
  for (int i = tid; i < 16 * 272; i += NTS)
    hpk[i] = (i < 8 * 272) ? 0 : (signed char)-128;

  // quantize weights; wave wv owns n-tiles wv*3..wv*3+2
  i32x4 breg[4];
  float Cn[3];
  #pragma unroll
  for (int t3 = 0; t3 < 3; ++t3) {
    int row = (wv * 3 + t3) * 16 + ncol;
    int sw = 0;
    #pragma unroll
    for (int c = 0; c < 4; ++c) {
      const float* p = w_hh + (size_t)row * HD + c * 64 + quad * 16;
      unsigned pw[4] = {0u, 0u, 0u, 0u};
      #pragma unroll
      for (int e = 0; e < 16; ++e) {
        int q = __float2int_rn(p[e] * 2048.f);       // w * 2^11
        q = max(-127, min(127, q));
        sw += q;
        pw[e >> 2] |= ((unsigned)(q & 255)) << ((e & 3) * 8);
      }
      i32x4 frag = (i32x4){(int)pw[0], (int)pw[1], (int)pw[2], (int)pw[3]};
      if (t3 == 0) breg[c] = frag;
      else {
        int base = (((wv * 2 + (t3 - 1)) * 4 + c) << 10) + lane * 16;
        *(i32x4*)&wlds[base] = frag;                 // wave-private, no barrier needed
      }
    }
    sw += __shfl_xor(sw, 16);
    sw += __shfl_xor(sw, 32);                        // full-K sum of q_w for row
    Cn[t3] = b_hh[row] + 128.f * (float)sw * INV26;
  }

  // gate identity: items (b0, j) and (b0+4, j); b0 = tid>>8 in 0..3
  int j = tid & 255, b0 = tid >> 8;
  float hreg[2] = {0.f, 0.f};
  float xrp[2], xzp[2], xnp[2];
  #pragma unroll
  for (int it = 0; it < 2; ++it) {
    int b = b0 + 4 * it;
    int v = x[b * SEQ];
    const float* tr = table + (size_t)v * G3 + j;
    xrp[it] = tr[0]; xzp[it] = tr[256]; xnp[it] = tr[512];
  }

  int a_base = ncol * 272 + quad * 16;

  for (int t = 0; t < SEQ; ++t) {
    __syncthreads();                                 // hpk ready
    i32x4 a[4];
    #pragma unroll
    for (int c = 0; c < 4; ++c)
      a[c] = *(const i32x4*)&hpk[a_base + c * 64];
    // tile 0 (register-resident weights)
    {
      i32x4 acc = {0, 0, 0, 0};
      #pragma unroll
      for (int c = 0; c < 4; ++c)
        acc = __builtin_amdgcn_mfma_i32_16x16x64_i8(a[c], breg[c], acc, 0, 0, 0);
      int n = (wv * 3) * 16 + ncol;
      #pragma unroll
      for (int i = 0; i < 4; ++i) {
        int ax = __shfl_xor(acc[i], 32);
        if (quad < 2)
          hg[(quad * 4 + i) * G3 + n] =
              ((float)acc[i] * 256.f + (float)ax) * INV26 + Cn[0];
      }
    }
    // tiles 1-2 (LDS-resident weights, wave-private)
    #pragma unroll
    for (int tt = 0; tt < 2; ++tt) {
      i32x4 acc = {0, 0, 0, 0};
      #pragma unroll
      for (int c = 0; c < 4; ++c) {
        i32x4 bf = *(const i32x4*)&wlds[(((wv * 2 + tt) * 4 + c) << 10) + lane * 16];
        acc = __builtin_amdgcn_mfma_i32_16x16x64_i8(a[c], bf, acc, 0, 0, 0);
      }
      int n = (wv * 3 + 1 + tt) * 16 + ncol;
      #pragma unroll
      for (int i = 0; i < 4; ++i) {
        int ax = __shfl_xor(acc[i], 32);
        if (quad < 2)
          hg[(quad * 4 + i) * G3 + n] =
              ((float)acc[i] * 256.f + (float)ax) * INV26 + Cn[1 + tt];
      }
    }
    __syncthreads();                                 // hg ready
    #pragma unroll
    for (int it = 0; it < 2; ++it) {
      int b = b0 + 4 * it;
      float hr = hg[b * G3 + j];
      float hz = hg[b * G3 + 256 + j];
      float hn = hg[b * G3 + 512 + j];
      float r = sigm(xrp[it] + hr);
      float z = sigm(xzp[it] + hz);
      float n = tanh_fast(xnp[it] + r * hn);
      float h = (1.f - z) * n + z * hreg[it];
      hreg[it] = h;
      int q = min(__float2int_rn(h * 32768.f), 32767);
      int lou = q & 255;
      int hi8 = (q - lou) >> 8;
      hpk[b * 272 + j] = (signed char)hi8;
      hpk[(b + 8) * 272 + j] = (signed char)(lou - 128);
      all_h[((size_t)b * SEQ + t) * HD + j] = h;
    }
    {                                                // prefetch next step's table rows
      int tn = (t + 1 < SEQ) ? t + 1 : t;
      #pragma unroll
      for (int it = 0; it < 2; ++it) {
        int b = b0 + 4 * it;
        int v = x[b * SEQ + tn];
        const float* tr = table + (size_t)v * G3 + j;
        xrp[it] = tr[0]; xzp[it] = tr[256]; xnp[it] = tr[512];
      }
    }
  }
  #pragma unroll
  for (int it = 0; it < 2; ++it) {
    int b = b0 + 4 * it;
    h_last[b * HD + j] = hreg[it];
  }
}

// ---------------- generic f32 GEMM  C[M,N] = A[M,K]·W[N,K]^T + bias
template<int ACT>
__global__ __launch_bounds__(256) void gemm_bias(
    const float* __restrict__ A, int lda,
    const float* __restrict__ W, const float* __restrict__ bias,
    float* __restrict__ C, int ldc, int N, int K) {
  __shared__ float As[128][36];
  __shared__ float Ws[64][36];
  int tid = threadIdx.x;
  int m0 = blockIdx.y * 128, n0 = blockIdx.x * 64;
  int ml = tid & 31, g = tid >> 5;
  float acc[4][8];
  #pragma unroll
  for (int i = 0; i < 4; ++i)
    #pragma unroll
    for (int jj = 0; jj < 8; ++jj) acc[i][jj] = 0.f;
  for (int k0 = 0; k0 < K; k0 += 32) {
    __syncthreads();
    #pragma unroll
    for (int i = 0; i < 4; ++i) {
      int idx = tid + i * 256;
      int r = idx >> 3, c4 = (idx & 7) * 4;
      *(f32x4*)&As[r][c4] = *(const f32x4*)&A[(size_t)(m0 + r) * lda + k0 + c4];
    }
    #pragma unroll
    for (int i = 0; i < 2; ++i) {
      int idx = tid + i * 256;
      int r = idx >> 3, c4 = (idx & 7) * 4;
      f32x4 wv = {0.f, 0.f, 0.f, 0.f};
      if (n0 + r < N) wv = *(const f32x4*)&W[(size_t)(n0 + r) * K + k0 + c4];
      *(f32x4*)&Ws[r][c4] = wv;
    }
    __syncthreads();
    #pragma unroll
    for (int k4 = 0; k4 < 32; k4 += 4) {
      f32x4 av[4], wv8[8];
      #pragma unroll
      for (int i = 0; i < 4; ++i) av[i] = *(const f32x4*)&As[ml + i * 32][k4];
      #pragma unroll
      for (int jj = 0; jj < 8; ++jj) wv8[jj] = *(const f32x4*)&Ws[g * 8 + jj][k4];
      #pragma unroll
      for (int kk = 0; kk < 4; ++kk)
        #pragma unroll
        for (int i = 0; i < 4; ++i)
          #pragma unroll
          for (int jj = 0; jj < 8; ++jj)
            acc[i][jj] += av[i][kk] * wv8[jj][kk];
    }
  }
  #pragma unroll
  for (int i = 0; i < 4; ++i) {
    int m = m0 + ml + i * 32;
    #pragma unroll
    for (int jj = 0; jj < 8; ++jj) {
      int n = n0 + g * 8 + jj;
      if (n < N) {
        float val = acc[i][jj] + bias[n];
        if (ACT) val = tanh_fast(val);
        C[(size_t)m * ldc + n] = val;
      }
    }
  }
}

// ---------------- comb GEMM: A = [all_h | ctx] split-K (K=512), tanh epilogue
__global__ __launch_bounds__(256) void gemm_bias_cat(
    const float* __restrict__ A1, const float* __restrict__ A2,
    const float* __restrict__ W, const float* __restrict__ bias,
    float* __restrict__ C) {
  __shared__ float As[128][36];
  __shared__ float Ws[64][36];
  const int K = 512;
  int tid = threadIdx.x;
  int m0 = blockIdx.y * 128, n0 = blockIdx.x * 64;
  int ml = tid & 31, g = tid >> 5;
  float acc[4][8];
  #pragma unroll
  for (int i = 0; i < 4; ++i)
    #pragma unroll
    for (int jj = 0; jj < 8; ++jj) acc[i][jj] = 0.f;
  for (int k0 = 0; k0 < K; k0 += 32) {
    const float* src = (k0 < 256) ? A1 : A2;
    int kb = (k0 < 256) ? k0 : k0 - 256;
    __syncthreads();
    #pragma unroll
    for (int i = 0; i < 4; ++i) {
      int idx = tid + i * 256;
      int r = idx >> 3, c4 = (idx & 7) * 4;
      *(f32x4*)&As[r][c4] = *(const f32x4*)&src[(size_t)(m0 + r) * 256 + kb + c4];
    }
    #pragma unroll
    for (int i = 0; i < 2; ++i) {
      int idx = tid + i * 256;
      int r = idx >> 3, c4 = (idx & 7) * 4;
      *(f32x4*)&Ws[r][c4] = *(const f32x4*)&W[(size_t)(n0 + r) * K + k0 + c4];
    }
    __syncthreads();
    #pragma unroll
    for (int k4 = 0; k4 < 32; k4 += 4) {
      f32x4 av[4], wv8[8];
      #pragma unroll
      for (int i = 0; i < 4; ++i) av[i] = *(const f32x4*)&As[ml + i * 32][k4];
      #pragma unroll
      for (int jj = 0; jj < 8; ++jj) wv8[jj] = *(const f32x4*)&Ws[g * 8 + jj][k4];
      #pragma unroll
      for (int kk = 0; kk < 4; ++kk)
        #pragma unroll
        for (int i = 0; i < 4; ++i)
          #pragma unroll
          for (int jj = 0; jj < 8; ++jj)
            acc[i][jj] += av[i][kk] * wv8[jj][kk];
    }
  }
  #pragma unroll
  for (int i = 0; i < 4; ++i) {
    int m = m0 + ml + i * 32;
    #pragma unroll
    for (int jj = 0; jj < 8; ++jj) {
      int n = n0 + g * 8 + jj;
      C[(size_t)m * 256 + n] = tanh_fast(acc[i][jj] + bias[n]);
    }
  }
}

// ---------------- K4: causal flash attention, q-tile 32 / k-tile 16, all f32.
// Qs/Ks XOR-swizzled -> conflict-free score loop.
__global__ __launch_bounds__(256) void attention_kernel(
    const float* __restrict__ all_h, const float* __restrict__ keys,
    float* __restrict__ ctx) {
  __shared__ float Qs[32 * 256];
  __shared__ float Ks[16 * 256];
  __shared__ float Hs[16 * 256];
  __shared__ float Sl[32][17];
  __shared__ float mL[32], lL[32], aL[32];
  int b = blockIdx.y, jb = blockIdx.x, tid = threadIdx.x;
  const float* hb = all_h + (size_t)b * SEQ * HD;
  const float* kb = keys  + (size_t)b * SEQ * HD;
  int qg = tid & 15, hi = tid >> 4;
  int r0 = qg * 2, r1 = r0 + 1;
  int sq = qg & 7;                          // Q swizzle bits for rows r0,r1
  for (int phase = 0; phase < 2; ++phase) {
    int qt = phase ? (63 - jb) : jb;
    int q0 = qt * 32;
    __syncthreads();
    #pragma unroll
    for (int i = 0; i < 8; ++i) {           // stage Q 32x256 (swizzled)
      int idx = tid + i * 256;
      int r = idx >> 6, cg = idx & 63;
      *(f32x4*)&Qs[r * 256 + ((cg ^ ((r >> 1) & 7)) << 2)] =
          *(const f32x4*)&hb[(size_t)(q0 + r) * HD + cg * 4];
    }
    if (tid < 32) { mL[tid] = -3e38f; lL[tid] = 0.f; }
    float O0[16], O1[16];
    #pragma unroll
    for (int c = 0; c < 16; ++c) { O0[c] = 0.f; O1[c] = 0.f; }
    int nkt = 2 * (qt + 1);
    for (int kt = 0; kt < nkt; ++kt) {
      int k0 = kt * 16;
      __syncthreads();
      #pragma unroll
      for (int i = 0; i < 4; ++i) {         // stage K (swizzled) + V, 16x256 each
        int idx = tid + i * 256;
        int r = idx >> 6, cg = idx & 63;
        *(f32x4*)&Ks[r * 256 + ((cg ^ (r & 7)) << 2)] =
            *(const f32x4*)&kb[(size_t)(k0 + r) * HD + cg * 4];
        *(f32x4*)&Hs[r * 256 + cg * 4] = *(const f32x4*)&hb[(size_t)(k0 + r) * HD + cg * 4];
      }
      __syncthreads();
      int kc = hi;
      int sk = kc & 7;
      float sc0 = 0.f, sc1 = 0.f;
      #pragma unroll 8
      for (int c = 0; c < 64; ++c) {
        f32x4 kv  = *(const f32x4*)&Ks[kc * 256 + ((c ^ sk) << 2)];
        f32x4 q0v = *(const f32x4*)&Qs[r0 * 256 + ((c ^ sq) << 2)];
        f32x4 q1v = *(const f32x4*)&Qs[r1 * 256 + ((c ^ sq) << 2)];
        sc0 += q0v[0]*kv[0] + q0v[1]*kv[1] + q0v[2]*kv[2] + q0v[3]*kv[3];
        sc1 += q1v[0]*kv[0] + q1v[1]*kv[1] + q1v[2]*kv[2] + q1v[3]*kv[3];
      }
      int kabs = k0 + kc;
      Sl[r0][kc] = (kabs <= q0 + r0) ? sc0 : -3e38f;
      Sl[r1][kc] = (kabs <= q0 + r1) ? sc1 : -3e38f;
      __syncthreads();
      if (tid < 32) {                       // online softmax per q-row
        float mo = mL[tid], mn = mo;
        #pragma unroll
        for (int c = 0; c < 16; ++c) mn = fmaxf(mn, Sl[tid][c]);
        float al = __expf(mo - mn);
        float sm = 0.f;
        #pragma unroll
        for (int c = 0; c < 16; ++c) {
          float p = __expf(Sl[tid][c] - mn);
          Sl[tid][c] = p; sm += p;
        }
        lL[tid] = lL[tid] * al + sm;
        mL[tid] = mn;
        aL[tid] = al;
      }
      __syncthreads();
      float a0 = aL[r0], a1 = aL[r1];
      #pragma unroll
      for (int c = 0; c < 16; ++c) { O0[c] *= a0; O1[c] *= a1; }
      #pragma unroll
      for (int k = 0; k < 16; ++k) {
        float p0 = Sl[r0][k], p1 = Sl[r1][k];
        #pragma unroll
        for (int c4 = 0; c4 < 4; ++c4) {
          f32x4 hh = *(const f32x4*)&Hs[k * 256 + hi * 16 + c4 * 4];
          O0[c4*4+0] += p0 * hh[0]; O0[c4*4+1] += p0 * hh[1];
          O0[c4*4+2] += p0 * hh[2]; O0[c4*4+3] += p0 * hh[3];
          O1[c4*4+0] += p1 * hh[0]; O1[c4*4+1] += p1 * hh[1];
          O1[c4*4+2] += p1 * hh[2]; O1[c4*4+3] += p1 * hh[3];
        }
      }
    }
    float li0 = 1.f / lL[r0], li1 = 1.f / lL[r1];
    float* d0 = &ctx[((size_t)b * SEQ + q0 + r0) * 256 + hi * 16];
    float* d1 = &ctx[((size_t)b * SEQ + q0 + r1) * 256 + hi * 16];
    #pragma unroll
    for (int c4 = 0; c4 < 4; ++c4) {
      f32x4 v0, v1;
      #pragma unroll
      for (int c = 0; c < 4; ++c) { v0[c] = O0[c4*4+c] * li0; v1[c] = O1[c4*4+c] * li1; }
      *(f32x4*)&d0[c4*4] = v0;
      *(f32x4*)&d1[c4*4] = v1;
    }
  }
}

extern "C" void kernel_launch(void* const* d_in, const int* in_sizes, int n_in,
                              void* d_out, int out_size, void* d_ws, size_t ws_size,
                              hipStream_t stream) {
  (void)in_sizes; (void)n_in; (void)out_size; (void)ws_size;
  const int*   x      = (const int*)  d_in[0];
  const float* emb    = (const float*)d_in[1];
  const float* w_ih   = (const float*)d_in[2];
  const float* w_hh   = (const float*)d_in[3];
  const float* b_ih   = (const float*)d_in[4];
  const float* b_hh   = (const float*)d_in[5];
  const float* attn_w = (const float*)d_in[6];
  const float* attn_b = (const float*)d_in[7];
  const float* comb_w = (const float*)d_in[8];
  const float* comb_b = (const float*)d_in[9];
  const float* fc_w   = (const float*)d_in[10];
  const float* fc_b   = (const float*)d_in[11];
  float* out = (float*)d_out;

  // workspace layout (floats): table | all_h | keys(->combined) | ctx
  float* ws    = (float*)d_ws;
  float* table = ws;                        // 100*768      =    76800
  float* all_h = table + 76800;             // 16384*256    =  4194304
  float* keys  = all_h + 4194304;           // 16384*256    =  4194304
  float* ctx   = keys  + 4194304;           // 16384*256    =  4194304
  float* hlast = out + (size_t)NB * SEQ * NV;

  build_table<<<100, 256, 0, stream>>>(emb, w_ih, b_ih, table);
  gru_scan<<<1, NTS, 0, stream>>>(x, w_hh, b_hh, table, all_h, hlast);
  // keys = all_h @ attn_w^T + attn_b
  gemm_bias<0><<<dim3(4, 128), 256, 0, stream>>>(all_h, 256, attn_w, attn_b, keys, 256, 256, 256);
  // ctx = softmax(causal(all_h @ keys^T)) @ all_h
  attention_kernel<<<dim3(32, 8), 256, 0, stream>>>(all_h, keys, ctx);
  // combined = tanh([all_h|ctx] @ comb_w^T + comb_b)  (into keys buffer)
  gemm_bias_cat<<<dim3(4, 128), 256, 0, stream>>>(all_h, ctx, comb_w, comb_b, keys);
  // out = combined @ fc_w^T + fc_b
  gemm_bias<0><<<dim3(2, 128), 256, 0, stream>>>(keys, 256, fc_w, fc_b, out, 100, 100, 256);
}

// Round 10
// 3068.168 us; speedup vs baseline: 5.6371x; 1.9797x over previous
//
#include <hip/hip_runtime.h>

#define SEQ  2048
#define NB   8
#define HD   256
#define G3   768
#define NV   100

typedef float f32x4 __attribute__((ext_vector_type(4)));
typedef int   i32x4 __attribute__((ext_vector_type(4)));

#define INV26 1.490116119384765625e-8f   // 2^-26

__device__ __forceinline__ float sigm(float x) {
  x = fminf(fmaxf(x, -30.f), 30.f);
  return 1.f / (1.f + __expf(-x));
}
__device__ __forceinline__ float tanh_fast(float x) {
  x = fminf(fmaxf(x, -15.f), 15.f);
  float e = __expf(2.f * x);
  return (e - 1.f) / (e + 1.f);
}

// ---------------- K1: xg lookup table: table[v][g] = emb[v]·w_ih[g] + b_ih[g]
__global__ __launch_bounds__(256) void build_table(
    const float* __restrict__ emb, const float* __restrict__ w_ih,
    const float* __restrict__ b_ih, float* __restrict__ table) {
  __shared__ float eL[256];
  __shared__ float wL[256][37];
  int v = blockIdx.x, tid = threadIdx.x;
  eL[tid] = emb[v * HD + tid];
  for (int gt = 0; gt < 3; ++gt) {
    float acc = b_ih[gt * 256 + tid];
    for (int e0 = 0; e0 < HD; e0 += 32) {
      __syncthreads();
      #pragma unroll
      for (int i = 0; i < 32; ++i) {
        int idx = tid + i * 256;
        int r = idx >> 5, c = idx & 31;
        wL[r][c] = w_ih[(size_t)(gt * 256 + r) * HD + e0 + c];
      }
      __syncthreads();
      #pragma unroll
      for (int c = 0; c < 32; ++c) acc += eL[e0 + c] * wL[tid][c];
    }
    table[(size_t)v * G3 + gt * 256 + tid] = acc;
  }
}

// ---------------- K2: batch-parallel GRU scan: one WG per batch (grid=8).
// The 8 recurrences are independent -> no cross-WG traffic. Each WG computes
// its batch's full 768x256 matvec per step; weights fully VGPR-resident:
// 48 n-tiles / 16 waves = 3 tiles x 4 chunks x 16B = 48 regs/lane (+~45
// working < the 128-reg budget the allocator honors at 16 waves). This kills
// the 128 KB/step LDS weight stream (192 ds_read_b128 ~ 2300 cyc) that bounded
// rounds 8-9 to ~5700 cyc/step on a single CU.
// Verified i8 math (rounds 8/9): q_w = round(w*2^11) single plane;
// q_h = hi8*256 + lou; A row 0 = hi8, row 8 = lou-128 (others zero);
// hg = (256*D0 + D8 + 128*sum_k q_w) * 2^-26 + b_hh.
// C/D: col=lane&15, row=(lane>>4)*4+reg; rows 0 and 8 differ by lane xor 32.
__global__ void __launch_bounds__(1024) gru_scan(
    const int* __restrict__ x, const float* __restrict__ w_hh,
    const float* __restrict__ b_hh, const float* __restrict__ table,
    float* __restrict__ all_h, float* __restrict__ h_last) {
  __shared__ __align__(16) signed char hpk[16 * 272];
  __shared__ float hg[G3];
  const int b = blockIdx.x;
  int tid = threadIdx.x;
  int lane = tid & 63, wv = tid >> 6;       // 16 waves
  int ncol = lane & 15, quad = lane >> 4;

  // init: row 0 (hi8) = 0, row 8 (lou-128) = -128, all other rows stay 0
  for (int i = tid; i < 16 * 272; i += 1024)
    hpk[i] = (i >= 8 * 272 && i < 9 * 272) ? (signed char)-128 : 0;

  // quantize weights into registers; wave wv owns n-tiles 3wv..3wv+2
  i32x4 bw[3][4];
  float Cn[3];
  #pragma unroll
  for (int t3 = 0; t3 < 3; ++t3) {
    int row = (wv * 3 + t3) * 16 + ncol;
    int sw = 0;
    #pragma unroll
    for (int c = 0; c < 4; ++c) {
      const float* p = w_hh + (size_t)row * HD + c * 64 + quad * 16;
      unsigned pw[4] = {0u, 0u, 0u, 0u};
      #pragma unroll
      for (int e = 0; e < 16; ++e) {
        int q = __float2int_rn(p[e] * 2048.f);       // w * 2^11
        q = max(-127, min(127, q));
        sw += q;
        pw[e >> 2] |= ((unsigned)(q & 255)) << ((e & 3) * 8);
      }
      bw[t3][c] = (i32x4){(int)pw[0], (int)pw[1], (int)pw[2], (int)pw[3]};
    }
    sw += __shfl_xor(sw, 16);
    sw += __shfl_xor(sw, 32);                        // full-K sum of q_w for row
    Cn[t3] = b_hh[row] + 128.f * (float)sw * INV26;
  }

  // gate identity: threads 0..255 handle hidden unit j = tid for batch b
  float hreg = 0.f, xr = 0.f, xz = 0.f, xn = 0.f;
  if (tid < 256) {
    int v = x[b * SEQ];
    const float* tr = table + (size_t)v * G3 + tid;
    xr = tr[0]; xz = tr[256]; xn = tr[512];
  }

  int a_base = ncol * 272 + quad * 16;

  for (int t = 0; t < SEQ; ++t) {
    __syncthreads();                                 // hpk ready
    i32x4 a[4];
    #pragma unroll
    for (int c = 0; c < 4; ++c)
      a[c] = *(const i32x4*)&hpk[a_base + c * 64];
    #pragma unroll
    for (int t3 = 0; t3 < 3; ++t3) {
      i32x4 acc = {0, 0, 0, 0};
      #pragma unroll
      for (int c = 0; c < 4; ++c)
        acc = __builtin_amdgcn_mfma_i32_16x16x64_i8(a[c], bw[t3][c], acc, 0, 0, 0);
      int ax = __shfl_xor(acc[0], 32);               // D row 8 (h-lo plane)
      if (quad == 0) {                               // D row 0 lives in quad 0, reg 0
        int n = (wv * 3 + t3) * 16 + ncol;
        hg[n] = ((float)acc[0] * 256.f + (float)ax) * INV26 + Cn[t3];
      }
    }
    __syncthreads();                                 // hg ready
    if (tid < 256) {
      int j = tid;
      float r = sigm(xr + hg[j]);
      float z = sigm(xz + hg[256 + j]);
      float n = tanh_fast(xn + r * hg[512 + j]);
      float h = (1.f - z) * n + z * hreg;
      hreg = h;
      int q = min(__float2int_rn(h * 32768.f), 32767);
      int lou = q & 255;
      int hi8 = (q - lou) >> 8;
      hpk[j] = (signed char)hi8;
      hpk[8 * 272 + j] = (signed char)(lou - 128);
      all_h[((size_t)b * SEQ + t) * HD + j] = h;
      int tn = (t + 1 < SEQ) ? t + 1 : t;            // prefetch next step's xg
      int v = x[b * SEQ + tn];
      const float* tr = table + (size_t)v * G3 + j;
      xr = tr[0]; xz = tr[256]; xn = tr[512];
    }
  }
  if (tid < 256) h_last[b * HD + tid] = hreg;
}

// ---------------- generic f32 GEMM  C[M,N] = A[M,K]·W[N,K]^T + bias
template<int ACT>
__global__ __launch_bounds__(256) void gemm_bias(
    const float* __restrict__ A, int lda,
    const float* __restrict__ W, const float* __restrict__ bias,
    float* __restrict__ C, int ldc, int N, int K) {
  __shared__ float As[128][36];
  __shared__ float Ws[64][36];
  int tid = threadIdx.x;
  int m0 = blockIdx.y * 128, n0 = blockIdx.x * 64;
  int ml = tid & 31, g = tid >> 5;
  float acc[4][8];
  #pragma unroll
  for (int i = 0; i < 4; ++i)
    #pragma unroll
    for (int jj = 0; jj < 8; ++jj) acc[i][jj] = 0.f;
  for (int k0 = 0; k0 < K; k0 += 32) {
    __syncthreads();
    #pragma unroll
    for (int i = 0; i < 4; ++i) {
      int idx = tid + i * 256;
      int r = idx >> 3, c4 = (idx & 7) * 4;
      *(f32x4*)&As[r][c4] = *(const f32x4*)&A[(size_t)(m0 + r) * lda + k0 + c4];
    }
    #pragma unroll
    for (int i = 0; i < 2; ++i) {
      int idx = tid + i * 256;
      int r = idx >> 3, c4 = (idx & 7) * 4;
      f32x4 wv = {0.f, 0.f, 0.f, 0.f};
      if (n0 + r < N) wv = *(const f32x4*)&W[(size_t)(n0 + r) * K + k0 + c4];
      *(f32x4*)&Ws[r][c4] = wv;
    }
    __syncthreads();
    #pragma unroll
    for (int k4 = 0; k4 < 32; k4 += 4) {
      f32x4 av[4], wv8[8];
      #pragma unroll
      for (int i = 0; i < 4; ++i) av[i] = *(const f32x4*)&As[ml + i * 32][k4];
      #pragma unroll
      for (int jj = 0; jj < 8; ++jj) wv8[jj] = *(const f32x4*)&Ws[g * 8 + jj][k4];
      #pragma unroll
      for (int kk = 0; kk < 4; ++kk)
        #pragma unroll
        for (int i = 0; i < 4; ++i)
          #pragma unroll
          for (int jj = 0; jj < 8; ++jj)
            acc[i][jj] += av[i][kk] * wv8[jj][kk];
    }
  }
  #pragma unroll
  for (int i = 0; i < 4; ++i) {
    int m = m0 + ml + i * 32;
    #pragma unroll
    for (int jj = 0; jj < 8; ++jj) {
      int n = n0 + g * 8 + jj;
      if (n < N) {
        float val = acc[i][jj] + bias[n];
        if (ACT) val = tanh_fast(val);
        C[(size_t)m * ldc + n] = val;
      }
    }
  }
}

// ---------------- comb GEMM: A = [all_h | ctx] split-K (K=512), tanh epilogue
__global__ __launch_bounds__(256) void gemm_bias_cat(
    const float* __restrict__ A1, const float* __restrict__ A2,
    const float* __restrict__ W, const float* __restrict__ bias,
    float* __restrict__ C) {
  __shared__ float As[128][36];
  __shared__ float Ws[64][36];
  const int K = 512;
  int tid = threadIdx.x;
  int m0 = blockIdx.y * 128, n0 = blockIdx.x * 64;
  int ml = tid & 31, g = tid >> 5;
  float acc[4][8];
  #pragma unroll
  for (int i = 0; i < 4; ++i)
    #pragma unroll
    for (int jj = 0; jj < 8; ++jj) acc[i][jj] = 0.f;
  for (int k0 = 0; k0 < K; k0 += 32) {
    const float* src = (k0 < 256) ? A1 : A2;
    int kb = (k0 < 256) ? k0 : k0 - 256;
    __syncthreads();
    #pragma unroll
    for (int i = 0; i < 4; ++i) {
      int idx = tid + i * 256;
      int r = idx >> 3, c4 = (idx & 7) * 4;
      *(f32x4*)&As[r][c4] = *(const f32x4*)&src[(size_t)(m0 + r) * 256 + kb + c4];
    }
    #pragma unroll
    for (int i = 0; i < 2; ++i) {
      int idx = tid + i * 256;
      int r = idx >> 3, c4 = (idx & 7) * 4;
      *(f32x4*)&Ws[r][c4] = *(const f32x4*)&W[(size_t)(n0 + r) * K + k0 + c4];
    }
    __syncthreads();
    #pragma unroll
    for (int k4 = 0; k4 < 32; k4 += 4) {
      f32x4 av[4], wv8[8];
      #pragma unroll
      for (int i = 0; i < 4; ++i) av[i] = *(const f32x4*)&As[ml + i * 32][k4];
      #pragma unroll
      for (int jj = 0; jj < 8; ++jj) wv8[jj] = *(const f32x4*)&Ws[g * 8 + jj][k4];
      #pragma unroll
      for (int kk = 0; kk < 4; ++kk)
        #pragma unroll
        for (int i = 0; i < 4; ++i)
          #pragma unroll
          for (int jj = 0; jj < 8; ++jj)
            acc[i][jj] += av[i][kk] * wv8[jj][kk];
    }
  }
  #pragma unroll
  for (int i = 0; i < 4; ++i) {
    int m = m0 + ml + i * 32;
    #pragma unroll
    for (int jj = 0; jj < 8; ++jj) {
      int n = n0 + g * 8 + jj;
      C[(size_t)m * 256 + n] = tanh_fast(acc[i][jj] + bias[n]);
    }
  }
}

// ---------------- K4: causal flash attention, q-tile 32 / k-tile 16, all f32.
// Qs/Ks XOR-swizzled -> conflict-free score loop.
__global__ __launch_bounds__(256) void attention_kernel(
    const float* __restrict__ all_h, const float* __restrict__ keys,
    float* __restrict__ ctx) {
  __shared__ float Qs[32 * 256];
  __shared__ float Ks[16 * 256];
  __shared__ float Hs[16 * 256];
  __shared__ float Sl[32][17];
  __shared__ float mL[32], lL[32], aL[32];
  int b = blockIdx.y, jb = blockIdx.x, tid = threadIdx.x;
  const float* hb = all_h + (size_t)b * SEQ * HD;
  const float* kb = keys  + (size_t)b * SEQ * HD;
  int qg = tid & 15, hi = tid >> 4;
  int r0 = qg * 2, r1 = r0 + 1;
  int sq = qg & 7;                          // Q swizzle bits for rows r0,r1
  for (int phase = 0; phase < 2; ++phase) {
    int qt = phase ? (63 - jb) : jb;
    int q0 = qt * 32;
    __syncthreads();
    #pragma unroll
    for (int i = 0; i < 8; ++i) {           // stage Q 32x256 (swizzled)
      int idx = tid + i * 256;
      int r = idx >> 6, cg = idx & 63;
      *(f32x4*)&Qs[r * 256 + ((cg ^ ((r >> 1) & 7)) << 2)] =
          *(const f32x4*)&hb[(size_t)(q0 + r) * HD + cg * 4];
    }
    if (tid < 32) { mL[tid] = -3e38f; lL[tid] = 0.f; }
    float O0[16], O1[16];
    #pragma unroll
    for (int c = 0; c < 16; ++c) { O0[c] = 0.f; O1[c] = 0.f; }
    int nkt = 2 * (qt + 1);
    for (int kt = 0; kt < nkt; ++kt) {
      int k0 = kt * 16;
      __syncthreads();
      #pragma unroll
      for (int i = 0; i < 4; ++i) {         // stage K (swizzled) + V, 16x256 each
        int idx = tid + i * 256;
        int r = idx >> 6, cg = idx & 63;
        *(f32x4*)&Ks[r * 256 + ((cg ^ (r & 7)) << 2)] =
            *(const f32x4*)&kb[(size_t)(k0 + r) * HD + cg * 4];
        *(f32x4*)&Hs[r * 256 + cg * 4] = *(const f32x4*)&hb[(size_t)(k0 + r) * HD + cg * 4];
      }
      __syncthreads();
      int kc = hi;
      int sk = kc & 7;
      float sc0 = 0.f, sc1 = 0.f;
      #pragma unroll 8
      for (int c = 0; c < 64; ++c) {
        f32x4 kv  = *(const f32x4*)&Ks[kc * 256 + ((c ^ sk) << 2)];
        f32x4 q0v = *(const f32x4*)&Qs[r0 * 256 + ((c ^ sq) << 2)];
        f32x4 q1v = *(const f32x4*)&Qs[r1 * 256 + ((c ^ sq) << 2)];
        sc0 += q0v[0]*kv[0] + q0v[1]*kv[1] + q0v[2]*kv[2] + q0v[3]*kv[3];
        sc1 += q1v[0]*kv[0] + q1v[1]*kv[1] + q1v[2]*kv[2] + q1v[3]*kv[3];
      }
      int kabs = k0 + kc;
      Sl[r0][kc] = (kabs <= q0 + r0) ? sc0 : -3e38f;
      Sl[r1][kc] = (kabs <= q0 + r1) ? sc1 : -3e38f;
      __syncthreads();
      if (tid < 32) {                       // online softmax per q-row
        float mo = mL[tid], mn = mo;
        #pragma unroll
        for (int c = 0; c < 16; ++c) mn = fmaxf(mn, Sl[tid][c]);
        float al = __expf(mo - mn);
        float sm = 0.f;
        #pragma unroll
        for (int c = 0; c < 16; ++c) {
          float p = __expf(Sl[tid][c] - mn);
          Sl[tid][c] = p; sm += p;
        }
        lL[tid] = lL[tid] * al + sm;
        mL[tid] = mn;
        aL[tid] = al;
      }
      __syncthreads();
      float a0 = aL[r0], a1 = aL[r1];
      #pragma unroll
      for (int c = 0; c < 16; ++c) { O0[c] *= a0; O1[c] *= a1; }
      #pragma unroll
      for (int k = 0; k < 16; ++k) {
        float p0 = Sl[r0][k], p1 = Sl[r1][k];
        #pragma unroll
        for (int c4 = 0; c4 < 4; ++c4) {
          f32x4 hh = *(const f32x4*)&Hs[k * 256 + hi * 16 + c4 * 4];
          O0[c4*4+0] += p0 * hh[0]; O0[c4*4+1] += p0 * hh[1];
          O0[c4*4+2] += p0 * hh[2]; O0[c4*4+3] += p0 * hh[3];
          O1[c4*4+0] += p1 * hh[0]; O1[c4*4+1] += p1 * hh[1];
          O1[c4*4+2] += p1 * hh[2]; O1[c4*4+3] += p1 * hh[3];
        }
      }
    }
    float li0 = 1.f / lL[r0], li1 = 1.f / lL[r1];
    float* d0 = &ctx[((size_t)b * SEQ + q0 + r0) * 256 + hi * 16];
    float* d1 = &ctx[((size_t)b * SEQ + q0 + r1) * 256 + hi * 16];
    #pragma unroll
    for (int c4 = 0; c4 < 4; ++c4) {
      f32x4 v0, v1;
      #pragma unroll
      for (int c = 0; c < 4; ++c) { v0[c] = O0[c4*4+c] * li0; v1[c] = O1[c4*4+c] * li1; }
      *(f32x4*)&d0[c4*4] = v0;
      *(f32x4*)&d1[c4*4] = v1;
    }
  }
}

extern "C" void kernel_launch(void* const* d_in, const int* in_sizes, int n_in,
                              void* d_out, int out_size, void* d_ws, size_t ws_size,
                              hipStream_t stream) {
  (void)in_sizes; (void)n_in; (void)out_size; (void)ws_size;
  const int*   x      = (const int*)  d_in[0];
  const float* emb    = (const float*)d_in[1];
  const float* w_ih   = (const float*)d_in[2];
  const float* w_hh   = (const float*)d_in[3];
  const float* b_ih   = (const float*)d_in[4];
  const float* b_hh   = (const float*)d_in[5];
  const float* attn_w = (const float*)d_in[6];
  const float* attn_b = (const float*)d_in[7];
  const float* comb_w = (const float*)d_in[8];
  const float* comb_b = (const float*)d_in[9];
  const float* fc_w   = (const float*)d_in[10];
  const float* fc_b   = (const float*)d_in[11];
  float* out = (float*)d_out;

  // workspace layout (floats): table | all_h | keys(->combined) | ctx
  float* ws    = (float*)d_ws;
  float* table = ws;                        // 100*768      =    76800
  float* all_h = table + 76800;             // 16384*256    =  4194304
  float* keys  = all_h + 4194304;           // 16384*256    =  4194304
  float* ctx   = keys  + 4194304;           // 16384*256    =  4194304
  float* hlast = out + (size_t)NB * SEQ * NV;

  build_table<<<100, 256, 0, stream>>>(emb, w_ih, b_ih, table);
  gru_scan<<<NB, 1024, 0, stream>>>(x, w_hh, b_hh, table, all_h, hlast);
  // keys = all_h @ attn_w^T + attn_b
  gemm_bias<0><<<dim3(4, 128), 256, 0, stream>>>(all_h, 256, attn_w, attn_b, keys, 256, 256, 256);
  // ctx = softmax(causal(all_h @ keys^T)) @ all_h
  attention_kernel<<<dim3(32, 8), 256, 0, stream>>>(all_h, keys, ctx);
  // combined = tanh([all_h|ctx] @ comb_w^T + comb_b)  (into keys buffer)
  gemm_bias_cat<<<dim3(4, 128), 256, 0, stream>>>(all_h, ctx, comb_w, comb_b, keys);
  // out = combined @ fc_w^T + fc_b
  gemm_bias<0><<<dim3(2, 128), 256, 0, stream>>>(keys, 256, fc_w, fc_b, out, 100, 100, 256);
}